// Round 7
// baseline (516.659 us; speedup 1.0000x reference)
//
#include <hip/hip_runtime.h>
#include <hip/hip_bf16.h>
#include <cstdint>
#include <cstddef>

// Problem constants
#define BMC 32    // B*M
#define NNODE 1024
#define DIN 128
#define PPROJ 64
#define NCLUS 10
#define FOUT 128
#define KNB 10

typedef _Float16 half8 __attribute__((ext_vector_type(8)));
typedef float f32x4 __attribute__((ext_vector_type(4)));

// Inputs: fp32 (probe-confirmed). Output: fp32. Internals fp32 except:
//  - Z stored as fp16 split pair Zh/Zl (lo scaled x2048) for MFMA Gram
//  - Ek bf16 (overlays dead Zh/Zl region after k_topk)
// X_trans fp32 (16 MB) lives in d_out; k_final overwrites d_out with output.
static const size_t OFF_Z    = 0;          // words [0,1048576): Zh fp16 [32,1024,64]; [1048576,2097152): Zl fp16
static const size_t OFF_SQ   = 2097152;    // 32,768     ||Z||^2 fp32
static const size_t OFF_HC   = 2129920;    // 327,680    softmax cluster H [32,1024,10] fp32
static const size_t OFF_IDX  = 2457600;    // 327,680    (int) knn indices [32,1024,10]
static const size_t OFF_CNT  = 2785280;    // 32,768     (int) edge in-degree  [ZEROED]
static const size_t OFF_FILL = 2818048;    // 32,768     (int) CSR fill ptrs   [ZEROED]
static const size_t OFF_EC   = 2850816;    // 40,960     cluster edge feats    [ZEROED]
static const size_t OFF_DCV  = 2891776;    // 320        cluster edge degrees  [ZEROED]
static const size_t OFF_OFFS = 2892096;    // 32,768     (int) CSR offsets
static const size_t OFF_ADJ  = 2924864;    // 327,680    (int) CSR adjacency (node ids)
static const size_t OFF_FLAG = 3252544;    // 1          (int) input-dtype flag
static const size_t OFF_END  = 3252608;
static const size_t ZERO_N   = OFF_OFFS - OFF_CNT;

__device__ __forceinline__ float bfu(unsigned int lo16) {
    return __uint_as_float(lo16 << 16);
}
__device__ __forceinline__ float bfhi(unsigned int w) {
    return __uint_as_float(w & 0xffff0000u);
}
__device__ __forceinline__ float ldf(const void* p, size_t i, bool isbf) {
    return isbf ? bfu((unsigned int)((const unsigned short*)p)[i])
                : ((const float*)p)[i];
}

// ---------------------------------------------------------------------------
__global__ __launch_bounds__(256) void k_probe(const unsigned int* __restrict__ xw,
                                               int* __restrict__ flag) {
    __shared__ int red[256];
    int t = threadIdx.x;
    int cnt = 0;
    for (int i = t; i < 1024; i += 256) {
        float b = bfu(xw[i] & 0xffffu);
        float ab = fabsf(b);
        if (ab > 9.5e-7f && ab < 1.0e6f) cnt++;
    }
    red[t] = cnt;
    __syncthreads();
    for (int off = 128; off > 0; off >>= 1) {
        if (t < off) red[t] += red[t + off];
        __syncthreads();
    }
    if (t == 0) flag[0] = (red[0] >= 700) ? 1 : 0;
}

__global__ __launch_bounds__(256) void k_zero(float* __restrict__ p, int n) {
    int i = blockIdx.x * 256 + threadIdx.x;
    if (i < n) p[i] = 0.0f;
}

// ---------------------------------------------------------------------------
// Kernel 1: Z = x_flat @ Wp^T + b ; sq = ||Z||^2 ; Hc = softmax(Z @ C^T)
// Z written as fp16 split (Zh, Zl*2048) for the MFMA Gram kernel.
// ---------------------------------------------------------------------------
__global__ __launch_bounds__(256) void k_proj(const void* __restrict__ x,
                                              const void* __restrict__ Wp,
                                              const void* __restrict__ Wpb,
                                              const void* __restrict__ Cm,
                                              const int* __restrict__ flag,
                                              _Float16* __restrict__ Zh,
                                              _Float16* __restrict__ Zl,
                                              float* __restrict__ sqv,
                                              float* __restrict__ Hc) {
    __shared__ float xs[32][132];
    __shared__ float wpT[128][65];
    __shared__ float cs[10][64];
    __shared__ float zs[32][68];

    const bool isbf = (flag[0] != 0);
    int tid = threadIdx.x;
    int bi  = blockIdx.x;
    int bm  = bi >> 5;
    int n0  = (bi & 31) << 5;
    int b   = bm >> 3, m = bm & 7;

    if (isbf) {
        const unsigned short* xp = (const unsigned short*)x;
        for (int e = tid; e < 512; e += 256) {
            int r = e >> 4, h = e & 15;
            uint4 u = *(const uint4*)(xp + ((((size_t)b * NNODE + n0 + r) * 8 + m) * DIN + h * 8));
            int c = h * 8;
            xs[r][c+0] = bfu(u.x & 0xffffu); xs[r][c+1] = bfhi(u.x);
            xs[r][c+2] = bfu(u.y & 0xffffu); xs[r][c+3] = bfhi(u.y);
            xs[r][c+4] = bfu(u.z & 0xffffu); xs[r][c+5] = bfhi(u.z);
            xs[r][c+6] = bfu(u.w & 0xffffu); xs[r][c+7] = bfhi(u.w);
        }
    } else {
        const float* xp = (const float*)x;
        for (int e = tid; e < 1024; e += 256) {
            int r = e >> 5, q = e & 31;
            *(float4*)&xs[r][q * 4] =
                *(const float4*)(xp + ((((size_t)b * NNODE + n0 + r) * 8 + m) * DIN + q * 4));
        }
    }
    for (int e = tid; e < 8192; e += 256) {
        int p = e >> 7, d = e & 127;
        wpT[d][p] = ldf(Wp, (size_t)p * 128 + d, isbf);
    }
    for (int e = tid; e < 640; e += 256) cs[e >> 6][e & 63] = ldf(Cm, e, isbf);
    __syncthreads();

    int rg = tid >> 6, p = tid & 63;
    float acc[8] = {0.f,0.f,0.f,0.f,0.f,0.f,0.f,0.f};
    for (int d4 = 0; d4 < 32; ++d4) {
        float w0 = wpT[d4*4+0][p], w1 = wpT[d4*4+1][p];
        float w2 = wpT[d4*4+2][p], w3 = wpT[d4*4+3][p];
#pragma unroll
        for (int j = 0; j < 8; ++j) {
            float4 xv = *(const float4*)&xs[rg*8+j][d4*4];
            acc[j] += xv.x*w0 + xv.y*w1 + xv.z*w2 + xv.w*w3;
        }
    }
    float bias = ldf(Wpb, p, isbf);
#pragma unroll
    for (int j = 0; j < 8; ++j) {
        float v = acc[j] + bias;
        zs[rg*8+j][p] = v;
        size_t off = ((size_t)bm * NNODE + n0 + rg*8 + j) * 64 + p;
        _Float16 h = (_Float16)v;
        _Float16 l = (_Float16)((v - (float)h) * 2048.0f);
        Zh[off] = h;
        Zl[off] = l;
    }
    __syncthreads();

    // per-row sq + cluster softmax: 8 threads per row (shuffles proven R4==R5)
    int row = tid >> 3, slot = tid & 7;
    int d0 = slot * 8;
    float sp = 0.f;
#pragma unroll
    for (int dd = 0; dd < 8; ++dd) { float z = zs[row][d0+dd]; sp += z * z; }
#pragma unroll
    for (int mm = 1; mm < 8; mm <<= 1) sp += __shfl_xor(sp, mm, 8);
    size_t g = (size_t)bm * NNODE + n0 + row;
    if (slot == 0) sqv[g] = sp;

    float sc[10];
#pragma unroll
    for (int c = 0; c < 10; ++c) {
        float pa = 0.f;
#pragma unroll
        for (int dd = 0; dd < 8; ++dd) pa += zs[row][d0+dd] * cs[c][d0+dd];
#pragma unroll
        for (int mm = 1; mm < 8; mm <<= 1) pa += __shfl_xor(pa, mm, 8);
        sc[c] = pa;
    }
    float mx = sc[0];
#pragma unroll
    for (int c = 1; c < 10; ++c) mx = fmaxf(mx, sc[c]);
    float ssum = 0.f;
#pragma unroll
    for (int c = 0; c < 10; ++c) { sc[c] = expf(sc[c] - mx); ssum += sc[c]; }
    float inv = 1.0f / ssum;
#pragma unroll
    for (int c = 0; c < 10; ++c)
        if ((c & 7) == slot) Hc[g * 10 + c] = sc[c] * inv;
}

// ---------------------------------------------------------------------------
// Kernel 2: X_trans = x_flat @ Theta^T + b  -> fp32 in d_out (unchanged)
// ---------------------------------------------------------------------------
__global__ __launch_bounds__(256) void k_theta(const void* __restrict__ x,
                                               const void* __restrict__ Th,
                                               const void* __restrict__ Thb,
                                               const int* __restrict__ flag,
                                               float* __restrict__ Xt) {
    __shared__ float xs[32][132];
    __shared__ float thT[64][132];

    const bool isbf = (flag[0] != 0);
    int tid = threadIdx.x;
    int bi  = blockIdx.x;
    int bm  = bi >> 5;
    int n0  = (bi & 31) << 5;
    int b   = bm >> 3, m = bm & 7;

    if (isbf) {
        const unsigned short* xp = (const unsigned short*)x;
        for (int e = tid; e < 512; e += 256) {
            int r = e >> 4, h = e & 15;
            uint4 u = *(const uint4*)(xp + ((((size_t)b * NNODE + n0 + r) * 8 + m) * DIN + h * 8));
            int c = h * 8;
            xs[r][c+0] = bfu(u.x & 0xffffu); xs[r][c+1] = bfhi(u.x);
            xs[r][c+2] = bfu(u.y & 0xffffu); xs[r][c+3] = bfhi(u.y);
            xs[r][c+4] = bfu(u.z & 0xffffu); xs[r][c+5] = bfhi(u.z);
            xs[r][c+6] = bfu(u.w & 0xffffu); xs[r][c+7] = bfhi(u.w);
        }
    } else {
        const float* xp = (const float*)x;
        for (int e = tid; e < 1024; e += 256) {
            int r = e >> 5, q = e & 31;
            *(float4*)&xs[r][q * 4] =
                *(const float4*)(xp + ((((size_t)b * NNODE + n0 + r) * 8 + m) * DIN + q * 4));
        }
    }

    int rg = tid >> 7, f = tid & 127;
    float acc[16];
#pragma unroll
    for (int j = 0; j < 16; ++j) acc[j] = 0.f;

    for (int kc = 0; kc < 2; ++kc) {
        __syncthreads();
        for (int e = tid; e < 8192; e += 256) {
            int ff = e >> 6, dk = e & 63;
            thT[dk][ff] = ldf(Th, (size_t)ff * 128 + kc * 64 + dk, isbf);
        }
        __syncthreads();
        for (int dk4 = 0; dk4 < 16; ++dk4) {
            float w0 = thT[dk4*4+0][f], w1 = thT[dk4*4+1][f];
            float w2 = thT[dk4*4+2][f], w3 = thT[dk4*4+3][f];
            int dbase = kc * 64 + dk4 * 4;
#pragma unroll
            for (int j = 0; j < 16; ++j) {
                float4 xv = *(const float4*)&xs[rg*16+j][dbase];
                acc[j] += xv.x*w0 + xv.y*w1 + xv.z*w2 + xv.w*w3;
            }
        }
    }
    float bias = ldf(Thb, f, isbf);
#pragma unroll
    for (int j = 0; j < 16; ++j)
        Xt[((size_t)bm * NNODE + n0 + rg*16 + j) * 128 + f] = acc[j] + bias;
}

// ---------------------------------------------------------------------------
// Kernel 3: fused Gram + top-K via fp16 split MFMA.
// block=256 (4 waves), grid = 32 bm * 16 row-tiles (64 rows each).
// g = hh + (h*l' + l*h')/2048 ; score s = sq_col - 2g (sq_row dropped: ordering
// per row unaffected — same as R6-passing code). Selection logic unchanged.
// A-frag layout: A[m=lane&15][k=quad*8+j]; C/D: col=lane&15, row=quad*4+reg
// (HW-verified, learn_hip m89/m91/m120).
// ---------------------------------------------------------------------------
__global__ __launch_bounds__(256) void k_topk(const _Float16* __restrict__ Zh,
                                              const _Float16* __restrict__ Zl,
                                              const float* __restrict__ sqv,
                                              int* __restrict__ idxo,
                                              int* __restrict__ cnt) {
    __shared__ _Float16 BH[64 * 72];   // B tile hi [col][k] stride 72
    __shared__ _Float16 BL[64 * 72];   // B tile lo
    __shared__ float    ST[64 * 68];   // scores transposed [col][row] stride 68
    __shared__ float    sqt[64];

    int tid = threadIdx.x;
    int bi  = blockIdx.x;
    int bm  = bi >> 4;
    int n0  = (bi & 15) << 6;
    const _Float16* Zhb = Zh + (size_t)bm * NNODE * 64;
    const _Float16* Zlb = Zl + (size_t)bm * NNODE * 64;

    int lane = tid & 63, wave = tid >> 6;
    int m16 = lane & 15, quad = lane >> 4;

    // A fragments: 16 rows per wave, K=64 (2 k-instr), hi+lo — live in regs.
    half8 ah0, ah1, al0, al1;
    {
        size_t abase = (size_t)(n0 + wave * 16 + m16) * 64 + quad * 8;
        ah0 = *(const half8*)(Zhb + abase);
        ah1 = *(const half8*)(Zhb + abase + 32);
        al0 = *(const half8*)(Zlb + abase);
        al1 = *(const half8*)(Zlb + abase + 32);
    }

    unsigned long long keys[10];
#pragma unroll
    for (int j = 0; j < 10; ++j) keys[j] = ~0ULL;

    int srow = tid >> 2, sslot = tid & 3;   // scan: 4 threads/row

    for (int t = 0; t < 16; ++t) {
        int j0 = t << 6;
        // stage 64 cols x 64 k (hi+lo): 512 uint4 each
        for (int e = tid; e < 512; e += 256) {
            int col = e >> 3, kc = e & 7;
            *(uint4*)&BH[col * 72 + kc * 8] =
                *(const uint4*)(Zhb + (size_t)(j0 + col) * 64 + kc * 8);
            *(uint4*)&BL[col * 72 + kc * 8] =
                *(const uint4*)(Zlb + (size_t)(j0 + col) * 64 + kc * 8);
        }
        if (tid < 64) sqt[tid] = sqv[(size_t)bm * NNODE + j0 + tid];
        __syncthreads();

        // 4 col-blocks of 16 per wave
        for (int cb = 0; cb < 4; ++cb) {
            int cl = cb * 16 + m16;
            const _Float16* pb = &BH[cl * 72 + quad * 8];
            const _Float16* pl = &BL[cl * 72 + quad * 8];
            half8 bh0 = *(const half8*)pb;
            half8 bh1 = *(const half8*)(pb + 32);
            half8 bl0 = *(const half8*)pl;
            half8 bl1 = *(const half8*)(pl + 32);
            f32x4 acc  = {0.f, 0.f, 0.f, 0.f};
            f32x4 accx = {0.f, 0.f, 0.f, 0.f};
            acc  = __builtin_amdgcn_mfma_f32_16x16x32_f16(ah0, bh0, acc, 0, 0, 0);
            acc  = __builtin_amdgcn_mfma_f32_16x16x32_f16(ah1, bh1, acc, 0, 0, 0);
            accx = __builtin_amdgcn_mfma_f32_16x16x32_f16(al0, bh0, accx, 0, 0, 0);
            accx = __builtin_amdgcn_mfma_f32_16x16x32_f16(ah0, bl0, accx, 0, 0, 0);
            accx = __builtin_amdgcn_mfma_f32_16x16x32_f16(al1, bh1, accx, 0, 0, 0);
            accx = __builtin_amdgcn_mfma_f32_16x16x32_f16(ah1, bl1, accx, 0, 0, 0);
            float sqc = sqt[cl];
            f32x4 sc;
#pragma unroll
            for (int r = 0; r < 4; ++r) {
                float g = acc[r] + accx[r] * (1.0f / 2048.0f);
                sc[r] = fmaf(-2.0f, g, sqc);
            }
            // scores transposed: row = wave*16 + quad*4 + r, col = cl
            *(f32x4*)&ST[cl * 68 + wave * 16 + quad * 4] = sc;
        }
        __syncthreads();

        // scan: 16 cols per thread (4 threads/row), insert into sorted top-10
        for (int i = 0; i < 16; ++i) {
            int c = sslot + (i << 2);
            float v = ST[c * 68 + srow];
            unsigned int bits = __float_as_uint(v);
            unsigned int s = (bits & 0x80000000u) ? ~bits : (bits | 0x80000000u);
            unsigned long long key =
                ((unsigned long long)s << 32) | (unsigned int)(j0 + c);
            if (key < keys[9]) {
                keys[9] = key;
#pragma unroll
                for (int j = 9; j > 0; --j) {
                    if (keys[j] < keys[j-1]) {
                        unsigned long long tk = keys[j];
                        keys[j] = keys[j-1]; keys[j-1] = tk;
                    }
                }
            }
        }
        __syncthreads();   // scans done before next tile's staging overwrites? (B disjoint from ST; protects ST vs next compute)
    }

    // merge 4 slots/row: 10 rounds of min-extraction (proven R6)
    for (int it = 0; it < 10; ++it) {
        unsigned long long mine = keys[0];
        unsigned long long best = mine;
#pragma unroll
        for (int mm = 1; mm < 4; mm <<= 1) {
            unsigned long long o = __shfl_xor(best, mm, 4);
            if (o < best) best = o;
        }
        if (best == mine) {
#pragma unroll
            for (int j = 0; j < 9; ++j) keys[j] = keys[j+1];
            keys[9] = ~0ULL;
        }
        if (sslot == 0) {
            int col = (int)(best & 0xFFFFFFFFu);
            idxo[((size_t)bm * NNODE + n0 + srow) * KNB + it] = col;
            atomicAdd(&cnt[bm * NNODE + col], 1);
        }
    }
}

// ---------------------------------------------------------------------------
// CSR build: per-bm exclusive scan of in-degrees, then fill (unchanged)
// ---------------------------------------------------------------------------
__global__ __launch_bounds__(256) void k_scan(const int* __restrict__ cnt,
                                              int* __restrict__ offs) {
    __shared__ int part[256];
    int bm = blockIdx.x, t = threadIdx.x;
    int base = bm * 1024 + t * 4;
    int c0 = cnt[base], c1 = cnt[base+1], c2 = cnt[base+2], c3 = cnt[base+3];
    int ps = c0 + c1 + c2 + c3;
    part[t] = ps;
    __syncthreads();
    for (int off = 1; off < 256; off <<= 1) {
        int add = (t >= off) ? part[t - off] : 0;
        __syncthreads();
        part[t] += add;
        __syncthreads();
    }
    int e0 = part[t] - ps;
    int gb = bm * (NNODE * KNB);
    offs[base]   = gb + e0;
    offs[base+1] = gb + e0 + c0;
    offs[base+2] = gb + e0 + c0 + c1;
    offs[base+3] = gb + e0 + c0 + c1 + c2;
}

__global__ __launch_bounds__(256) void k_fill(const int* __restrict__ idxb,
                                              const int* __restrict__ offs,
                                              int* __restrict__ fill,
                                              int* __restrict__ adj) {
    int i = blockIdx.x * 256 + threadIdx.x;
    int g = i / 10;
    int bm = g >> 10;
    int e  = idxb[i];
    int eg = (bm << 10) + e;
    int pos = atomicAdd(&fill[eg], 1);
    adj[offs[eg] + pos] = g;
}

// ---------------------------------------------------------------------------
// kNN edge gather: Ek[e] = (1/De) * sum Xt[members]   (bf16 out, unchanged)
// ---------------------------------------------------------------------------
__global__ __launch_bounds__(256) void k_edge(const float* __restrict__ Xt,
                                              const int* __restrict__ offs,
                                              const int* __restrict__ cnt,
                                              const int* __restrict__ adj,
                                              __hip_bfloat16* __restrict__ Ek) {
    int tid = threadIdx.x;
    int e = blockIdx.x * 2 + (tid >> 7);
    int f = tid & 127;
    int start = offs[e];
    int num = cnt[e];
    float acc = 0.f;
    for (int i = 0; i < num; ++i) {
        int g = adj[start + i];
        acc += Xt[(size_t)g * 128 + f];
    }
    float scale = (num > 0) ? 1.0f / (float)num : 0.0f;
    Ek[(size_t)e * 128 + f] = __float2bfloat16(acc * scale);
}

// ---------------------------------------------------------------------------
// Cluster edges (unchanged)
// ---------------------------------------------------------------------------
__global__ __launch_bounds__(256) void k_clus(const float* __restrict__ Xt,
                                              const float* __restrict__ Hc,
                                              float* __restrict__ Ec,
                                              float* __restrict__ Dcv) {
    int tid = threadIdx.x;
    int bm = blockIdx.x >> 3;
    int ch = blockIdx.x & 7;
    int f = tid & 127;
    int h = tid >> 7;
    int c0 = h * 5;
    float acc[5]  = {0.f,0.f,0.f,0.f,0.f};
    float dacc[5] = {0.f,0.f,0.f,0.f,0.f};
    int n0 = ch * 128;
    for (int n = n0; n < n0 + 128; ++n) {
        size_t g = (size_t)bm * NNODE + n;
        float xv = Xt[g * 128 + f];
#pragma unroll
        for (int j = 0; j < 5; ++j) {
            float hv = Hc[g * 10 + c0 + j];
            acc[j]  += hv * xv;
            dacc[j] += hv;
        }
    }
#pragma unroll
    for (int j = 0; j < 5; ++j)
        atomicAdd(&Ec[((size_t)bm * 10 + c0 + j) * 128 + f], acc[j]);
    if (f == 0) {
#pragma unroll
        for (int j = 0; j < 5; ++j) atomicAdd(&Dcv[bm * 10 + c0 + j], dacc[j]);
    }
}

__global__ __launch_bounds__(256) void k_escale(float* __restrict__ Ec,
                                                const float* __restrict__ Dcv) {
    int i = blockIdx.x * 256 + threadIdx.x;
    float d = Dcv[i >> 7];
    Ec[i] = (d > 0.f) ? Ec[i] / d : 0.f;
}

// ---------------------------------------------------------------------------
// Final: node gather + ELU + transpose (unchanged)
// ---------------------------------------------------------------------------
__global__ __launch_bounds__(256) void k_final(const unsigned short* __restrict__ Ek,
                                               const float* __restrict__ Ec,
                                               const float* __restrict__ Hc,
                                               const int* __restrict__ idxb,
                                               float* __restrict__ out) {
    int tid = threadIdx.x;
    int g = blockIdx.x * 2 + (tid >> 7);
    int f = tid & 127;
    int bm = g >> 10, n = g & 1023;
    const int* ip = idxb + (size_t)g * 10;
    float acc = 0.f;
#pragma unroll
    for (int k = 0; k < 10; ++k) {
        int e = ip[k];
        acc += bfu((unsigned int)Ek[((size_t)(bm << 10) + e) * 128 + f]);
    }
    const float* hp  = Hc + (size_t)g * 10;
    const float* ecp = Ec + (size_t)bm * 10 * 128 + f;
#pragma unroll
    for (int c = 0; c < 10; ++c) acc += hp[c] * ecp[c * 128];
    float r = acc * (1.0f / 11.0f);
    r = (r > 0.f) ? r : expm1f(r);
    int b = bm >> 3, m = bm & 7;
    out[(((size_t)b * NNODE + n) * 8 + m) * 128 + f] = r;
}

// ---------------------------------------------------------------------------
extern "C" void kernel_launch(void* const* d_in, const int* in_sizes, int n_in,
                              void* d_out, int out_size, void* d_ws, size_t ws_size,
                              hipStream_t stream) {
    const void* x   = d_in[0];
    const void* Wp  = d_in[1];
    const void* Wpb = d_in[2];
    const void* Cm  = d_in[3];
    const void* Th  = d_in[4];
    const void* Thb = d_in[5];
    float* ws = (float*)d_ws;

    if (ws_size < OFF_END * sizeof(float)) return;

    _Float16* Zh = (_Float16*)(ws + OFF_Z);             // 4 MB
    _Float16* Zl = (_Float16*)(ws + OFF_Z + 1048576);   // 4 MB
    float* sqv  = ws + OFF_SQ;
    float* Hc   = ws + OFF_HC;
    int*   idxb = (int*)(ws + OFF_IDX);
    int*   cnt  = (int*)(ws + OFF_CNT);
    int*   fill = (int*)(ws + OFF_FILL);
    float* Ec   = ws + OFF_EC;
    float* Dcv  = ws + OFF_DCV;
    int*   offs = (int*)(ws + OFF_OFFS);
    int*   adj  = (int*)(ws + OFF_ADJ);
    int*   flag = (int*)(ws + OFF_FLAG);
    __hip_bfloat16* Ek = (__hip_bfloat16*)(ws + OFF_Z); // overlays dead Zh/Zl
    float* Xt  = (float*)d_out;
    float* out = (float*)d_out;

    k_probe <<<1, 256, 0, stream>>>((const unsigned int*)x, flag);
    k_zero  <<<(int)((ZERO_N + 255) / 256), 256, 0, stream>>>(ws + OFF_CNT, (int)ZERO_N);
    k_proj  <<<1024, 256, 0, stream>>>(x, Wp, Wpb, Cm, flag, Zh, Zl, sqv, Hc);
    k_topk  <<<512,  256, 0, stream>>>(Zh, Zl, sqv, idxb, cnt);
    k_scan  <<<32,   256, 0, stream>>>(cnt, offs);
    k_fill  <<<1280, 256, 0, stream>>>(idxb, offs, fill, adj);
    k_theta <<<1024, 256, 0, stream>>>(x, Th, Thb, flag, Xt);
    k_edge  <<<16384,256, 0, stream>>>(Xt, offs, cnt, adj, Ek);
    k_clus  <<<256,  256, 0, stream>>>(Xt, Hc, Ec, Dcv);
    k_escale<<<160,  256, 0, stream>>>(Ec, Dcv);
    k_final <<<16384,256, 0, stream>>>((const unsigned short*)Ek, Ec, Hc, idxb, out);
}

// Round 8
// 444.119 us; speedup vs baseline: 1.1633x; 1.1633x over previous
//
#include <hip/hip_runtime.h>
#include <hip/hip_bf16.h>
#include <cstdint>
#include <cstddef>

// Problem constants
#define BMC 32    // B*M
#define NNODE 1024
#define DIN 128
#define PPROJ 64
#define NCLUS 10
#define FOUT 128
#define KNB 10

typedef _Float16 half8 __attribute__((ext_vector_type(8)));
typedef float f32x4 __attribute__((ext_vector_type(4)));

// Inputs: fp32 (probe-confirmed). Output: fp32. Internals fp32 except:
//  - Z stored as fp16 split pair Zh/Zl (lo scaled x2048) for MFMA Gram
//  - Ek bf16 (overlays dead Zh/Zl region after k_topk)
// X_trans fp32 (16 MB) lives in d_out; k_final overwrites d_out with output.
static const size_t OFF_Z    = 0;          // words [0,1048576): Zh fp16; [1048576,2097152): Zl fp16
static const size_t OFF_SQ   = 2097152;    // 32,768     ||Z||^2 fp32
static const size_t OFF_HC   = 2129920;    // 327,680    softmax cluster H fp32
static const size_t OFF_IDX  = 2457600;    // 327,680    (int) knn indices
static const size_t OFF_CNT  = 2785280;    // 32,768     (int) edge in-degree  [ZEROED]
static const size_t OFF_FILL = 2818048;    // 32,768     (int) CSR fill ptrs   [ZEROED]
static const size_t OFF_EC   = 2850816;    // 40,960     cluster edge feats    [ZEROED]
static const size_t OFF_DCV  = 2891776;    // 320        cluster edge degrees  [ZEROED]
static const size_t OFF_OFFS = 2892096;    // 32,768     (int) CSR offsets
static const size_t OFF_ADJ  = 2924864;    // 327,680    (int) CSR adjacency
static const size_t OFF_FLAG = 3252544;    // 1          (int) input-dtype flag
static const size_t OFF_END  = 3252608;
static const size_t ZERO_N   = OFF_OFFS - OFF_CNT;

__device__ __forceinline__ float bfu(unsigned int lo16) {
    return __uint_as_float(lo16 << 16);
}
__device__ __forceinline__ float bfhi(unsigned int w) {
    return __uint_as_float(w & 0xffff0000u);
}
__device__ __forceinline__ float ldf(const void* p, size_t i, bool isbf) {
    return isbf ? bfu((unsigned int)((const unsigned short*)p)[i])
                : ((const float*)p)[i];
}

// ---------------------------------------------------------------------------
__global__ __launch_bounds__(256) void k_probe(const unsigned int* __restrict__ xw,
                                               int* __restrict__ flag) {
    __shared__ int red[256];
    int t = threadIdx.x;
    int cnt = 0;
    for (int i = t; i < 1024; i += 256) {
        float b = bfu(xw[i] & 0xffffu);
        float ab = fabsf(b);
        if (ab > 9.5e-7f && ab < 1.0e6f) cnt++;
    }
    red[t] = cnt;
    __syncthreads();
    for (int off = 128; off > 0; off >>= 1) {
        if (t < off) red[t] += red[t + off];
        __syncthreads();
    }
    if (t == 0) flag[0] = (red[0] >= 700) ? 1 : 0;
}

__global__ __launch_bounds__(256) void k_zero(float* __restrict__ p, int n) {
    int i = blockIdx.x * 256 + threadIdx.x;
    if (i < n) p[i] = 0.0f;
}

// ---------------------------------------------------------------------------
// Kernel 1: Z = x_flat @ Wp^T + b ; sq = ||Z||^2 ; Hc = softmax(Z @ C^T)
// Z written as fp16 split (Zh, Zl*2048). (unchanged from R7 — passed)
// ---------------------------------------------------------------------------
__global__ __launch_bounds__(256) void k_proj(const void* __restrict__ x,
                                              const void* __restrict__ Wp,
                                              const void* __restrict__ Wpb,
                                              const void* __restrict__ Cm,
                                              const int* __restrict__ flag,
                                              _Float16* __restrict__ Zh,
                                              _Float16* __restrict__ Zl,
                                              float* __restrict__ sqv,
                                              float* __restrict__ Hc) {
    __shared__ float xs[32][132];
    __shared__ float wpT[128][65];
    __shared__ float cs[10][64];
    __shared__ float zs[32][68];

    const bool isbf = (flag[0] != 0);
    int tid = threadIdx.x;
    int bi  = blockIdx.x;
    int bm  = bi >> 5;
    int n0  = (bi & 31) << 5;
    int b   = bm >> 3, m = bm & 7;

    if (isbf) {
        const unsigned short* xp = (const unsigned short*)x;
        for (int e = tid; e < 512; e += 256) {
            int r = e >> 4, h = e & 15;
            uint4 u = *(const uint4*)(xp + ((((size_t)b * NNODE + n0 + r) * 8 + m) * DIN + h * 8));
            int c = h * 8;
            xs[r][c+0] = bfu(u.x & 0xffffu); xs[r][c+1] = bfhi(u.x);
            xs[r][c+2] = bfu(u.y & 0xffffu); xs[r][c+3] = bfhi(u.y);
            xs[r][c+4] = bfu(u.z & 0xffffu); xs[r][c+5] = bfhi(u.z);
            xs[r][c+6] = bfu(u.w & 0xffffu); xs[r][c+7] = bfhi(u.w);
        }
    } else {
        const float* xp = (const float*)x;
        for (int e = tid; e < 1024; e += 256) {
            int r = e >> 5, q = e & 31;
            *(float4*)&xs[r][q * 4] =
                *(const float4*)(xp + ((((size_t)b * NNODE + n0 + r) * 8 + m) * DIN + q * 4));
        }
    }
    for (int e = tid; e < 8192; e += 256) {
        int p = e >> 7, d = e & 127;
        wpT[d][p] = ldf(Wp, (size_t)p * 128 + d, isbf);
    }
    for (int e = tid; e < 640; e += 256) cs[e >> 6][e & 63] = ldf(Cm, e, isbf);
    __syncthreads();

    int rg = tid >> 6, p = tid & 63;
    float acc[8] = {0.f,0.f,0.f,0.f,0.f,0.f,0.f,0.f};
    for (int d4 = 0; d4 < 32; ++d4) {
        float w0 = wpT[d4*4+0][p], w1 = wpT[d4*4+1][p];
        float w2 = wpT[d4*4+2][p], w3 = wpT[d4*4+3][p];
#pragma unroll
        for (int j = 0; j < 8; ++j) {
            float4 xv = *(const float4*)&xs[rg*8+j][d4*4];
            acc[j] += xv.x*w0 + xv.y*w1 + xv.z*w2 + xv.w*w3;
        }
    }
    float bias = ldf(Wpb, p, isbf);
#pragma unroll
    for (int j = 0; j < 8; ++j) {
        float v = acc[j] + bias;
        zs[rg*8+j][p] = v;
        size_t off = ((size_t)bm * NNODE + n0 + rg*8 + j) * 64 + p;
        _Float16 h = (_Float16)v;
        _Float16 l = (_Float16)((v - (float)h) * 2048.0f);
        Zh[off] = h;
        Zl[off] = l;
    }
    __syncthreads();

    int row = tid >> 3, slot = tid & 7;
    int d0 = slot * 8;
    float sp = 0.f;
#pragma unroll
    for (int dd = 0; dd < 8; ++dd) { float z = zs[row][d0+dd]; sp += z * z; }
#pragma unroll
    for (int mm = 1; mm < 8; mm <<= 1) sp += __shfl_xor(sp, mm, 8);
    size_t g = (size_t)bm * NNODE + n0 + row;
    if (slot == 0) sqv[g] = sp;

    float sc[10];
#pragma unroll
    for (int c = 0; c < 10; ++c) {
        float pa = 0.f;
#pragma unroll
        for (int dd = 0; dd < 8; ++dd) pa += zs[row][d0+dd] * cs[c][d0+dd];
#pragma unroll
        for (int mm = 1; mm < 8; mm <<= 1) pa += __shfl_xor(pa, mm, 8);
        sc[c] = pa;
    }
    float mx = sc[0];
#pragma unroll
    for (int c = 1; c < 10; ++c) mx = fmaxf(mx, sc[c]);
    float ssum = 0.f;
#pragma unroll
    for (int c = 0; c < 10; ++c) { sc[c] = expf(sc[c] - mx); ssum += sc[c]; }
    float inv = 1.0f / ssum;
#pragma unroll
    for (int c = 0; c < 10; ++c)
        if ((c & 7) == slot) Hc[g * 10 + c] = sc[c] * inv;
}

// ---------------------------------------------------------------------------
// Kernel 2: X_trans = x_flat @ Theta^T + b  -> fp32 in d_out (unchanged)
// ---------------------------------------------------------------------------
__global__ __launch_bounds__(256) void k_theta(const void* __restrict__ x,
                                               const void* __restrict__ Th,
                                               const void* __restrict__ Thb,
                                               const int* __restrict__ flag,
                                               float* __restrict__ Xt) {
    __shared__ float xs[32][132];
    __shared__ float thT[64][132];

    const bool isbf = (flag[0] != 0);
    int tid = threadIdx.x;
    int bi  = blockIdx.x;
    int bm  = bi >> 5;
    int n0  = (bi & 31) << 5;
    int b   = bm >> 3, m = bm & 7;

    if (isbf) {
        const unsigned short* xp = (const unsigned short*)x;
        for (int e = tid; e < 512; e += 256) {
            int r = e >> 4, h = e & 15;
            uint4 u = *(const uint4*)(xp + ((((size_t)b * NNODE + n0 + r) * 8 + m) * DIN + h * 8));
            int c = h * 8;
            xs[r][c+0] = bfu(u.x & 0xffffu); xs[r][c+1] = bfhi(u.x);
            xs[r][c+2] = bfu(u.y & 0xffffu); xs[r][c+3] = bfhi(u.y);
            xs[r][c+4] = bfu(u.z & 0xffffu); xs[r][c+5] = bfhi(u.z);
            xs[r][c+6] = bfu(u.w & 0xffffu); xs[r][c+7] = bfhi(u.w);
        }
    } else {
        const float* xp = (const float*)x;
        for (int e = tid; e < 1024; e += 256) {
            int r = e >> 5, q = e & 31;
            *(float4*)&xs[r][q * 4] =
                *(const float4*)(xp + ((((size_t)b * NNODE + n0 + r) * 8 + m) * DIN + q * 4));
        }
    }

    int rg = tid >> 7, f = tid & 127;
    float acc[16];
#pragma unroll
    for (int j = 0; j < 16; ++j) acc[j] = 0.f;

    for (int kc = 0; kc < 2; ++kc) {
        __syncthreads();
        for (int e = tid; e < 8192; e += 256) {
            int ff = e >> 6, dk = e & 63;
            thT[dk][ff] = ldf(Th, (size_t)ff * 128 + kc * 64 + dk, isbf);
        }
        __syncthreads();
        for (int dk4 = 0; dk4 < 16; ++dk4) {
            float w0 = thT[dk4*4+0][f], w1 = thT[dk4*4+1][f];
            float w2 = thT[dk4*4+2][f], w3 = thT[dk4*4+3][f];
            int dbase = kc * 64 + dk4 * 4;
#pragma unroll
            for (int j = 0; j < 16; ++j) {
                float4 xv = *(const float4*)&xs[rg*16+j][dbase];
                acc[j] += xv.x*w0 + xv.y*w1 + xv.z*w2 + xv.w*w3;
            }
        }
    }
    float bias = ldf(Thb, f, isbf);
#pragma unroll
    for (int j = 0; j < 16; ++j)
        Xt[((size_t)bm * NNODE + n0 + rg*16 + j) * 128 + f] = acc[j] + bias;
}

// ---------------------------------------------------------------------------
// Kernel 3: fused Gram + top-K via fp16 split MFMA — parallelism-first rework.
// grid = 32 bm * 64 row-tiles (16 rows each) = 2048 blocks, block = 256.
// Selection: 16 threads/row -> only 64 candidate steps per wave.
// Merge: 10 rounds width-16 shuffle min-extract.
// ---------------------------------------------------------------------------
__global__ __launch_bounds__(256) void k_topk(const _Float16* __restrict__ Zh,
                                              const _Float16* __restrict__ Zl,
                                              const float* __restrict__ sqv,
                                              int* __restrict__ idxo,
                                              int* __restrict__ cnt) {
    __shared__ _Float16 BH[64 * 72];   // B hi [col][k], stride 72 halves (16B-aligned rows)
    __shared__ _Float16 BL[64 * 72];   // B lo
    __shared__ float    ST[64 * 20];   // scores [col][row(16)+pad]
    __shared__ float    sqt[64];

    int tid = threadIdx.x;
    int bi  = blockIdx.x;
    int bm  = bi >> 6;
    int n0  = (bi & 63) << 4;          // 16 rows per block
    const _Float16* Zhb = Zh + (size_t)bm * NNODE * 64;
    const _Float16* Zlb = Zl + (size_t)bm * NNODE * 64;

    int lane = tid & 63, wave = tid >> 6;
    int m16 = lane & 15, quad = lane >> 4;

    // A fragments: the block's 16 rows (same for all 4 waves), K=64, hi+lo.
    half8 ah0, ah1, al0, al1;
    {
        size_t ab = (size_t)(n0 + m16) * 64 + quad * 8;
        ah0 = *(const half8*)(Zhb + ab);
        ah1 = *(const half8*)(Zhb + ab + 32);
        al0 = *(const half8*)(Zlb + ab);
        al1 = *(const half8*)(Zlb + ab + 32);
    }

    unsigned long long keys[10];
#pragma unroll
    for (int j = 0; j < 10; ++j) keys[j] = ~0ULL;

    int srow  = tid >> 4;   // 0..15: row within block
    int sslot = tid & 15;   // 16 threads per row

    for (int t = 0; t < 16; ++t) {
        int j0 = t << 6;
        // stage 64 cols x 64 k (hi+lo): 512 uint4 each -> 2 per thread per array
        for (int e = tid; e < 512; e += 256) {
            int col = e >> 3, kc = e & 7;
            *(uint4*)&BH[col * 72 + kc * 8] =
                *(const uint4*)(Zhb + (size_t)(j0 + col) * 64 + kc * 8);
            *(uint4*)&BL[col * 72 + kc * 8] =
                *(const uint4*)(Zlb + (size_t)(j0 + col) * 64 + kc * 8);
        }
        if (tid < 64) sqt[tid] = sqv[(size_t)bm * NNODE + j0 + tid];
        __syncthreads();

        // compute: wave w covers cols w*16 + m16 of this 64-col tile
        {
            int cl = wave * 16 + m16;
            const _Float16* pb = &BH[cl * 72 + quad * 8];
            const _Float16* pl = &BL[cl * 72 + quad * 8];
            half8 bh0 = *(const half8*)pb;
            half8 bh1 = *(const half8*)(pb + 32);
            half8 bl0 = *(const half8*)pl;
            half8 bl1 = *(const half8*)(pl + 32);
            f32x4 acc  = {0.f, 0.f, 0.f, 0.f};
            f32x4 accx = {0.f, 0.f, 0.f, 0.f};
            acc  = __builtin_amdgcn_mfma_f32_16x16x32_f16(ah0, bh0, acc, 0, 0, 0);
            acc  = __builtin_amdgcn_mfma_f32_16x16x32_f16(ah1, bh1, acc, 0, 0, 0);
            accx = __builtin_amdgcn_mfma_f32_16x16x32_f16(al0, bh0, accx, 0, 0, 0);
            accx = __builtin_amdgcn_mfma_f32_16x16x32_f16(ah0, bl0, accx, 0, 0, 0);
            accx = __builtin_amdgcn_mfma_f32_16x16x32_f16(al1, bh1, accx, 0, 0, 0);
            accx = __builtin_amdgcn_mfma_f32_16x16x32_f16(ah1, bl1, accx, 0, 0, 0);
            float sqc = sqt[cl];
            f32x4 sc;
#pragma unroll
            for (int r = 0; r < 4; ++r) {
                float g = acc[r] + accx[r] * (1.0f / 2048.0f);
                sc[r] = fmaf(-2.0f, g, sqc);
            }
            // C/D layout: col=lane&15 (cl), rows quad*4+r -> transposed store
            *(f32x4*)&ST[cl * 20 + quad * 4] = sc;
        }
        __syncthreads();

        // selection: 4 cols per thread (16 threads/row)
#pragma unroll
        for (int i = 0; i < 4; ++i) {
            int c = sslot + (i << 4);
            float v = ST[c * 20 + srow];
            unsigned int bits = __float_as_uint(v);
            unsigned int s = (bits & 0x80000000u) ? ~bits : (bits | 0x80000000u);
            unsigned long long key =
                ((unsigned long long)s << 32) | (unsigned int)(j0 + c);
            if (key < keys[9]) {
                keys[9] = key;
#pragma unroll
                for (int j = 9; j > 0; --j) {
                    if (keys[j] < keys[j-1]) {
                        unsigned long long tk = keys[j];
                        keys[j] = keys[j-1]; keys[j-1] = tk;
                    }
                }
            }
        }
        // no barrier needed: next staging writes BH/BL (disjoint from ST);
        // next ST write is fenced by the staging barrier.
    }

    // merge 16 sorted lists per row: 10 rounds of width-16 min-extraction
    size_t gr = (size_t)bm * NNODE + n0 + srow;
    for (int it = 0; it < 10; ++it) {
        unsigned long long mine = keys[0];
        unsigned long long best = mine;
#pragma unroll
        for (int mm = 1; mm < 16; mm <<= 1) {
            unsigned long long o = __shfl_xor(best, mm, 16);
            if (o < best) best = o;
        }
        if (best == mine) {   // unique winner (col encoded in key)
#pragma unroll
            for (int j = 0; j < 9; ++j) keys[j] = keys[j+1];
            keys[9] = ~0ULL;
            int col = (int)(best & 0xFFFFFFFFu);
            idxo[gr * KNB + it] = col;
            atomicAdd(&cnt[bm * NNODE + col], 1);
        }
    }
}

// ---------------------------------------------------------------------------
// CSR build (unchanged)
// ---------------------------------------------------------------------------
__global__ __launch_bounds__(256) void k_scan(const int* __restrict__ cnt,
                                              int* __restrict__ offs) {
    __shared__ int part[256];
    int bm = blockIdx.x, t = threadIdx.x;
    int base = bm * 1024 + t * 4;
    int c0 = cnt[base], c1 = cnt[base+1], c2 = cnt[base+2], c3 = cnt[base+3];
    int ps = c0 + c1 + c2 + c3;
    part[t] = ps;
    __syncthreads();
    for (int off = 1; off < 256; off <<= 1) {
        int add = (t >= off) ? part[t - off] : 0;
        __syncthreads();
        part[t] += add;
        __syncthreads();
    }
    int e0 = part[t] - ps;
    int gb = bm * (NNODE * KNB);
    offs[base]   = gb + e0;
    offs[base+1] = gb + e0 + c0;
    offs[base+2] = gb + e0 + c0 + c1;
    offs[base+3] = gb + e0 + c0 + c1 + c2;
}

__global__ __launch_bounds__(256) void k_fill(const int* __restrict__ idxb,
                                              const int* __restrict__ offs,
                                              int* __restrict__ fill,
                                              int* __restrict__ adj) {
    int i = blockIdx.x * 256 + threadIdx.x;
    int g = i / 10;
    int bm = g >> 10;
    int e  = idxb[i];
    int eg = (bm << 10) + e;
    int pos = atomicAdd(&fill[eg], 1);
    adj[offs[eg] + pos] = g;
}

// ---------------------------------------------------------------------------
// kNN edge gather (unchanged)
// ---------------------------------------------------------------------------
__global__ __launch_bounds__(256) void k_edge(const float* __restrict__ Xt,
                                              const int* __restrict__ offs,
                                              const int* __restrict__ cnt,
                                              const int* __restrict__ adj,
                                              __hip_bfloat16* __restrict__ Ek) {
    int tid = threadIdx.x;
    int e = blockIdx.x * 2 + (tid >> 7);
    int f = tid & 127;
    int start = offs[e];
    int num = cnt[e];
    float acc = 0.f;
    for (int i = 0; i < num; ++i) {
        int g = adj[start + i];
        acc += Xt[(size_t)g * 128 + f];
    }
    float scale = (num > 0) ? 1.0f / (float)num : 0.0f;
    Ek[(size_t)e * 128 + f] = __float2bfloat16(acc * scale);
}

// ---------------------------------------------------------------------------
// Cluster edges (unchanged)
// ---------------------------------------------------------------------------
__global__ __launch_bounds__(256) void k_clus(const float* __restrict__ Xt,
                                              const float* __restrict__ Hc,
                                              float* __restrict__ Ec,
                                              float* __restrict__ Dcv) {
    int tid = threadIdx.x;
    int bm = blockIdx.x >> 3;
    int ch = blockIdx.x & 7;
    int f = tid & 127;
    int h = tid >> 7;
    int c0 = h * 5;
    float acc[5]  = {0.f,0.f,0.f,0.f,0.f};
    float dacc[5] = {0.f,0.f,0.f,0.f,0.f};
    int n0 = ch * 128;
    for (int n = n0; n < n0 + 128; ++n) {
        size_t g = (size_t)bm * NNODE + n;
        float xv = Xt[g * 128 + f];
#pragma unroll
        for (int j = 0; j < 5; ++j) {
            float hv = Hc[g * 10 + c0 + j];
            acc[j]  += hv * xv;
            dacc[j] += hv;
        }
    }
#pragma unroll
    for (int j = 0; j < 5; ++j)
        atomicAdd(&Ec[((size_t)bm * 10 + c0 + j) * 128 + f], acc[j]);
    if (f == 0) {
#pragma unroll
        for (int j = 0; j < 5; ++j) atomicAdd(&Dcv[bm * 10 + c0 + j], dacc[j]);
    }
}

__global__ __launch_bounds__(256) void k_escale(float* __restrict__ Ec,
                                                const float* __restrict__ Dcv) {
    int i = blockIdx.x * 256 + threadIdx.x;
    float d = Dcv[i >> 7];
    Ec[i] = (d > 0.f) ? Ec[i] / d : 0.f;
}

// ---------------------------------------------------------------------------
// Final: node gather + ELU + transpose (unchanged)
// ---------------------------------------------------------------------------
__global__ __launch_bounds__(256) void k_final(const unsigned short* __restrict__ Ek,
                                               const float* __restrict__ Ec,
                                               const float* __restrict__ Hc,
                                               const int* __restrict__ idxb,
                                               float* __restrict__ out) {
    int tid = threadIdx.x;
    int g = blockIdx.x * 2 + (tid >> 7);
    int f = tid & 127;
    int bm = g >> 10, n = g & 1023;
    const int* ip = idxb + (size_t)g * 10;
    float acc = 0.f;
#pragma unroll
    for (int k = 0; k < 10; ++k) {
        int e = ip[k];
        acc += bfu((unsigned int)Ek[((size_t)(bm << 10) + e) * 128 + f]);
    }
    const float* hp  = Hc + (size_t)g * 10;
    const float* ecp = Ec + (size_t)bm * 10 * 128 + f;
#pragma unroll
    for (int c = 0; c < 10; ++c) acc += hp[c] * ecp[c * 128];
    float r = acc * (1.0f / 11.0f);
    r = (r > 0.f) ? r : expm1f(r);
    int b = bm >> 3, m = bm & 7;
    out[(((size_t)b * NNODE + n) * 8 + m) * 128 + f] = r;
}

// ---------------------------------------------------------------------------
extern "C" void kernel_launch(void* const* d_in, const int* in_sizes, int n_in,
                              void* d_out, int out_size, void* d_ws, size_t ws_size,
                              hipStream_t stream) {
    const void* x   = d_in[0];
    const void* Wp  = d_in[1];
    const void* Wpb = d_in[2];
    const void* Cm  = d_in[3];
    const void* Th  = d_in[4];
    const void* Thb = d_in[5];
    float* ws = (float*)d_ws;

    if (ws_size < OFF_END * sizeof(float)) return;

    _Float16* Zh = (_Float16*)(ws + OFF_Z);
    _Float16* Zl = (_Float16*)(ws + OFF_Z + 1048576);
    float* sqv  = ws + OFF_SQ;
    float* Hc   = ws + OFF_HC;
    int*   idxb = (int*)(ws + OFF_IDX);
    int*   cnt  = (int*)(ws + OFF_CNT);
    int*   fill = (int*)(ws + OFF_FILL);
    float* Ec   = ws + OFF_EC;
    float* Dcv  = ws + OFF_DCV;
    int*   offs = (int*)(ws + OFF_OFFS);
    int*   adj  = (int*)(ws + OFF_ADJ);
    int*   flag = (int*)(ws + OFF_FLAG);
    __hip_bfloat16* Ek = (__hip_bfloat16*)(ws + OFF_Z); // overlays dead Zh/Zl
    float* Xt  = (float*)d_out;
    float* out = (float*)d_out;

    k_probe <<<1, 256, 0, stream>>>((const unsigned int*)x, flag);
    k_zero  <<<(int)((ZERO_N + 255) / 256), 256, 0, stream>>>(ws + OFF_CNT, (int)ZERO_N);
    k_proj  <<<1024, 256, 0, stream>>>(x, Wp, Wpb, Cm, flag, Zh, Zl, sqv, Hc);
    k_topk  <<<2048, 256, 0, stream>>>(Zh, Zl, sqv, idxb, cnt);
    k_scan  <<<32,   256, 0, stream>>>(cnt, offs);
    k_fill  <<<1280, 256, 0, stream>>>(idxb, offs, fill, adj);
    k_theta <<<1024, 256, 0, stream>>>(x, Th, Thb, flag, Xt);
    k_edge  <<<16384,256, 0, stream>>>(Xt, offs, cnt, adj, Ek);
    k_clus  <<<256,  256, 0, stream>>>(Xt, Hc, Ec, Dcv);
    k_escale<<<160,  256, 0, stream>>>(Ec, Dcv);
    k_final <<<16384,256, 0, stream>>>((const unsigned short*)Ek, Ec, Hc, idxb, out);
}

// Round 9
// 378.063 us; speedup vs baseline: 1.3666x; 1.1747x over previous
//
#include <hip/hip_runtime.h>
#include <hip/hip_bf16.h>
#include <cstdint>
#include <cstddef>

// Problem constants
#define BMC 32    // B*M
#define NNODE 1024
#define DIN 128
#define PPROJ 64
#define NCLUS 10
#define FOUT 128
#define KNB 10

typedef _Float16 half8 __attribute__((ext_vector_type(8)));
typedef float f32x4 __attribute__((ext_vector_type(4)));

// Inputs: fp32 (probe-confirmed). Output: fp32. Internals fp32 except:
//  - Z stored as fp16 split pair Zh/Zl (lo scaled x2048) for MFMA Gram
//  - Ek bf16 (overlays dead Zh/Zl region after k_topk)
// X_trans fp32 (16 MB) lives in d_out; k_final overwrites d_out with output.
static const size_t OFF_Z    = 0;          // words [0,1048576): Zh fp16; [1048576,2097152): Zl fp16
static const size_t OFF_SQ   = 2097152;    // 32,768     ||Z||^2 fp32
static const size_t OFF_HC   = 2129920;    // 327,680    softmax cluster H fp32
static const size_t OFF_IDX  = 2457600;    // 327,680    (int) knn indices
static const size_t OFF_CNT  = 2785280;    // 32,768     (int) edge in-degree  [ZEROED]
static const size_t OFF_FILL = 2818048;    // 32,768     (int) CSR fill ptrs   [ZEROED]
static const size_t OFF_EC   = 2850816;    // 40,960     cluster edge feats    [ZEROED]
static const size_t OFF_DCV  = 2891776;    // 320        cluster edge degrees  [ZEROED]
static const size_t OFF_OFFS = 2892096;    // 32,768     (int) CSR offsets
static const size_t OFF_ADJ  = 2924864;    // 327,680    (int) CSR adjacency
static const size_t OFF_FLAG = 3252544;    // 1          (int) input-dtype flag
static const size_t OFF_END  = 3252608;
static const size_t ZERO_N   = OFF_OFFS - OFF_CNT;

__device__ __forceinline__ float bfu(unsigned int lo16) {
    return __uint_as_float(lo16 << 16);
}
__device__ __forceinline__ float bfhi(unsigned int w) {
    return __uint_as_float(w & 0xffff0000u);
}
__device__ __forceinline__ float ldf(const void* p, size_t i, bool isbf) {
    return isbf ? bfu((unsigned int)((const unsigned short*)p)[i])
                : ((const float*)p)[i];
}
__device__ __forceinline__ unsigned short f2bf(float v) {
    __hip_bfloat16 h = __float2bfloat16(v);
    return *(unsigned short*)&h;
}

// ---------------------------------------------------------------------------
__global__ __launch_bounds__(256) void k_probe(const unsigned int* __restrict__ xw,
                                               int* __restrict__ flag) {
    __shared__ int red[256];
    int t = threadIdx.x;
    int cnt = 0;
    for (int i = t; i < 1024; i += 256) {
        float b = bfu(xw[i] & 0xffffu);
        float ab = fabsf(b);
        if (ab > 9.5e-7f && ab < 1.0e6f) cnt++;
    }
    red[t] = cnt;
    __syncthreads();
    for (int off = 128; off > 0; off >>= 1) {
        if (t < off) red[t] += red[t + off];
        __syncthreads();
    }
    if (t == 0) flag[0] = (red[0] >= 700) ? 1 : 0;
}

__global__ __launch_bounds__(256) void k_zero(float* __restrict__ p, int n) {
    int i = blockIdx.x * 256 + threadIdx.x;
    if (i < n) p[i] = 0.0f;
}

// ---------------------------------------------------------------------------
// Kernel 1: Z = x_flat @ Wp^T + b ; sq = ||Z||^2 ; Hc = softmax(Z @ C^T)
// (unchanged — passed R7/R8)
// ---------------------------------------------------------------------------
__global__ __launch_bounds__(256) void k_proj(const void* __restrict__ x,
                                              const void* __restrict__ Wp,
                                              const void* __restrict__ Wpb,
                                              const void* __restrict__ Cm,
                                              const int* __restrict__ flag,
                                              _Float16* __restrict__ Zh,
                                              _Float16* __restrict__ Zl,
                                              float* __restrict__ sqv,
                                              float* __restrict__ Hc) {
    __shared__ float xs[32][132];
    __shared__ float wpT[128][65];
    __shared__ float cs[10][64];
    __shared__ float zs[32][68];

    const bool isbf = (flag[0] != 0);
    int tid = threadIdx.x;
    int bi  = blockIdx.x;
    int bm  = bi >> 5;
    int n0  = (bi & 31) << 5;
    int b   = bm >> 3, m = bm & 7;

    if (isbf) {
        const unsigned short* xp = (const unsigned short*)x;
        for (int e = tid; e < 512; e += 256) {
            int r = e >> 4, h = e & 15;
            uint4 u = *(const uint4*)(xp + ((((size_t)b * NNODE + n0 + r) * 8 + m) * DIN + h * 8));
            int c = h * 8;
            xs[r][c+0] = bfu(u.x & 0xffffu); xs[r][c+1] = bfhi(u.x);
            xs[r][c+2] = bfu(u.y & 0xffffu); xs[r][c+3] = bfhi(u.y);
            xs[r][c+4] = bfu(u.z & 0xffffu); xs[r][c+5] = bfhi(u.z);
            xs[r][c+6] = bfu(u.w & 0xffffu); xs[r][c+7] = bfhi(u.w);
        }
    } else {
        const float* xp = (const float*)x;
        for (int e = tid; e < 1024; e += 256) {
            int r = e >> 5, q = e & 31;
            *(float4*)&xs[r][q * 4] =
                *(const float4*)(xp + ((((size_t)b * NNODE + n0 + r) * 8 + m) * DIN + q * 4));
        }
    }
    for (int e = tid; e < 8192; e += 256) {
        int p = e >> 7, d = e & 127;
        wpT[d][p] = ldf(Wp, (size_t)p * 128 + d, isbf);
    }
    for (int e = tid; e < 640; e += 256) cs[e >> 6][e & 63] = ldf(Cm, e, isbf);
    __syncthreads();

    int rg = tid >> 6, p = tid & 63;
    float acc[8] = {0.f,0.f,0.f,0.f,0.f,0.f,0.f,0.f};
    for (int d4 = 0; d4 < 32; ++d4) {
        float w0 = wpT[d4*4+0][p], w1 = wpT[d4*4+1][p];
        float w2 = wpT[d4*4+2][p], w3 = wpT[d4*4+3][p];
#pragma unroll
        for (int j = 0; j < 8; ++j) {
            float4 xv = *(const float4*)&xs[rg*8+j][d4*4];
            acc[j] += xv.x*w0 + xv.y*w1 + xv.z*w2 + xv.w*w3;
        }
    }
    float bias = ldf(Wpb, p, isbf);
#pragma unroll
    for (int j = 0; j < 8; ++j) {
        float v = acc[j] + bias;
        zs[rg*8+j][p] = v;
        size_t off = ((size_t)bm * NNODE + n0 + rg*8 + j) * 64 + p;
        _Float16 h = (_Float16)v;
        _Float16 l = (_Float16)((v - (float)h) * 2048.0f);
        Zh[off] = h;
        Zl[off] = l;
    }
    __syncthreads();

    int row = tid >> 3, slot = tid & 7;
    int d0 = slot * 8;
    float sp = 0.f;
#pragma unroll
    for (int dd = 0; dd < 8; ++dd) { float z = zs[row][d0+dd]; sp += z * z; }
#pragma unroll
    for (int mm = 1; mm < 8; mm <<= 1) sp += __shfl_xor(sp, mm, 8);
    size_t g = (size_t)bm * NNODE + n0 + row;
    if (slot == 0) sqv[g] = sp;

    float sc[10];
#pragma unroll
    for (int c = 0; c < 10; ++c) {
        float pa = 0.f;
#pragma unroll
        for (int dd = 0; dd < 8; ++dd) pa += zs[row][d0+dd] * cs[c][d0+dd];
#pragma unroll
        for (int mm = 1; mm < 8; mm <<= 1) pa += __shfl_xor(pa, mm, 8);
        sc[c] = pa;
    }
    float mx = sc[0];
#pragma unroll
    for (int c = 1; c < 10; ++c) mx = fmaxf(mx, sc[c]);
    float ssum = 0.f;
#pragma unroll
    for (int c = 0; c < 10; ++c) { sc[c] = expf(sc[c] - mx); ssum += sc[c]; }
    float inv = 1.0f / ssum;
#pragma unroll
    for (int c = 0; c < 10; ++c)
        if ((c & 7) == slot) Hc[g * 10 + c] = sc[c] * inv;
}

// ---------------------------------------------------------------------------
// Kernel 2: X_trans = x_flat @ Theta^T + b  -> fp32 in d_out (unchanged)
// ---------------------------------------------------------------------------
__global__ __launch_bounds__(256) void k_theta(const void* __restrict__ x,
                                               const void* __restrict__ Th,
                                               const void* __restrict__ Thb,
                                               const int* __restrict__ flag,
                                               float* __restrict__ Xt) {
    __shared__ float xs[32][132];
    __shared__ float thT[64][132];

    const bool isbf = (flag[0] != 0);
    int tid = threadIdx.x;
    int bi  = blockIdx.x;
    int bm  = bi >> 5;
    int n0  = (bi & 31) << 5;
    int b   = bm >> 3, m = bm & 7;

    if (isbf) {
        const unsigned short* xp = (const unsigned short*)x;
        for (int e = tid; e < 512; e += 256) {
            int r = e >> 4, h = e & 15;
            uint4 u = *(const uint4*)(xp + ((((size_t)b * NNODE + n0 + r) * 8 + m) * DIN + h * 8));
            int c = h * 8;
            xs[r][c+0] = bfu(u.x & 0xffffu); xs[r][c+1] = bfhi(u.x);
            xs[r][c+2] = bfu(u.y & 0xffffu); xs[r][c+3] = bfhi(u.y);
            xs[r][c+4] = bfu(u.z & 0xffffu); xs[r][c+5] = bfhi(u.z);
            xs[r][c+6] = bfu(u.w & 0xffffu); xs[r][c+7] = bfhi(u.w);
        }
    } else {
        const float* xp = (const float*)x;
        for (int e = tid; e < 1024; e += 256) {
            int r = e >> 5, q = e & 31;
            *(float4*)&xs[r][q * 4] =
                *(const float4*)(xp + ((((size_t)b * NNODE + n0 + r) * 8 + m) * DIN + q * 4));
        }
    }

    int rg = tid >> 7, f = tid & 127;
    float acc[16];
#pragma unroll
    for (int j = 0; j < 16; ++j) acc[j] = 0.f;

    for (int kc = 0; kc < 2; ++kc) {
        __syncthreads();
        for (int e = tid; e < 8192; e += 256) {
            int ff = e >> 6, dk = e & 63;
            thT[dk][ff] = ldf(Th, (size_t)ff * 128 + kc * 64 + dk, isbf);
        }
        __syncthreads();
        for (int dk4 = 0; dk4 < 16; ++dk4) {
            float w0 = thT[dk4*4+0][f], w1 = thT[dk4*4+1][f];
            float w2 = thT[dk4*4+2][f], w3 = thT[dk4*4+3][f];
            int dbase = kc * 64 + dk4 * 4;
#pragma unroll
            for (int j = 0; j < 16; ++j) {
                float4 xv = *(const float4*)&xs[rg*16+j][dbase];
                acc[j] += xv.x*w0 + xv.y*w1 + xv.z*w2 + xv.w*w3;
            }
        }
    }
    float bias = ldf(Thb, f, isbf);
#pragma unroll
    for (int j = 0; j < 16; ++j)
        Xt[((size_t)bm * NNODE + n0 + rg*16 + j) * 128 + f] = acc[j] + bias;
}

// ---------------------------------------------------------------------------
// Kernel 3: fused Gram + top-K via fp16 split MFMA (unchanged from R8)
// ---------------------------------------------------------------------------
__global__ __launch_bounds__(256) void k_topk(const _Float16* __restrict__ Zh,
                                              const _Float16* __restrict__ Zl,
                                              const float* __restrict__ sqv,
                                              int* __restrict__ idxo,
                                              int* __restrict__ cnt) {
    __shared__ _Float16 BH[64 * 72];
    __shared__ _Float16 BL[64 * 72];
    __shared__ float    ST[64 * 20];
    __shared__ float    sqt[64];

    int tid = threadIdx.x;
    int bi  = blockIdx.x;
    int bm  = bi >> 6;
    int n0  = (bi & 63) << 4;
    const _Float16* Zhb = Zh + (size_t)bm * NNODE * 64;
    const _Float16* Zlb = Zl + (size_t)bm * NNODE * 64;

    int lane = tid & 63, wave = tid >> 6;
    int m16 = lane & 15, quad = lane >> 4;

    half8 ah0, ah1, al0, al1;
    {
        size_t ab = (size_t)(n0 + m16) * 64 + quad * 8;
        ah0 = *(const half8*)(Zhb + ab);
        ah1 = *(const half8*)(Zhb + ab + 32);
        al0 = *(const half8*)(Zlb + ab);
        al1 = *(const half8*)(Zlb + ab + 32);
    }

    unsigned long long keys[10];
#pragma unroll
    for (int j = 0; j < 10; ++j) keys[j] = ~0ULL;

    int srow  = tid >> 4;
    int sslot = tid & 15;

    for (int t = 0; t < 16; ++t) {
        int j0 = t << 6;
        for (int e = tid; e < 512; e += 256) {
            int col = e >> 3, kc = e & 7;
            *(uint4*)&BH[col * 72 + kc * 8] =
                *(const uint4*)(Zhb + (size_t)(j0 + col) * 64 + kc * 8);
            *(uint4*)&BL[col * 72 + kc * 8] =
                *(const uint4*)(Zlb + (size_t)(j0 + col) * 64 + kc * 8);
        }
        if (tid < 64) sqt[tid] = sqv[(size_t)bm * NNODE + j0 + tid];
        __syncthreads();

        {
            int cl = wave * 16 + m16;
            const _Float16* pb = &BH[cl * 72 + quad * 8];
            const _Float16* pl = &BL[cl * 72 + quad * 8];
            half8 bh0 = *(const half8*)pb;
            half8 bh1 = *(const half8*)(pb + 32);
            half8 bl0 = *(const half8*)pl;
            half8 bl1 = *(const half8*)(pl + 32);
            f32x4 acc  = {0.f, 0.f, 0.f, 0.f};
            f32x4 accx = {0.f, 0.f, 0.f, 0.f};
            acc  = __builtin_amdgcn_mfma_f32_16x16x32_f16(ah0, bh0, acc, 0, 0, 0);
            acc  = __builtin_amdgcn_mfma_f32_16x16x32_f16(ah1, bh1, acc, 0, 0, 0);
            accx = __builtin_amdgcn_mfma_f32_16x16x32_f16(al0, bh0, accx, 0, 0, 0);
            accx = __builtin_amdgcn_mfma_f32_16x16x32_f16(ah0, bl0, accx, 0, 0, 0);
            accx = __builtin_amdgcn_mfma_f32_16x16x32_f16(al1, bh1, accx, 0, 0, 0);
            accx = __builtin_amdgcn_mfma_f32_16x16x32_f16(ah1, bl1, accx, 0, 0, 0);
            float sqc = sqt[cl];
            f32x4 sc;
#pragma unroll
            for (int r = 0; r < 4; ++r) {
                float g = acc[r] + accx[r] * (1.0f / 2048.0f);
                sc[r] = fmaf(-2.0f, g, sqc);
            }
            *(f32x4*)&ST[cl * 20 + quad * 4] = sc;
        }
        __syncthreads();

#pragma unroll
        for (int i = 0; i < 4; ++i) {
            int c = sslot + (i << 4);
            float v = ST[c * 20 + srow];
            unsigned int bits = __float_as_uint(v);
            unsigned int s = (bits & 0x80000000u) ? ~bits : (bits | 0x80000000u);
            unsigned long long key =
                ((unsigned long long)s << 32) | (unsigned int)(j0 + c);
            if (key < keys[9]) {
                keys[9] = key;
#pragma unroll
                for (int j = 9; j > 0; --j) {
                    if (keys[j] < keys[j-1]) {
                        unsigned long long tk = keys[j];
                        keys[j] = keys[j-1]; keys[j-1] = tk;
                    }
                }
            }
        }
    }

    size_t gr = (size_t)bm * NNODE + n0 + srow;
    for (int it = 0; it < 10; ++it) {
        unsigned long long mine = keys[0];
        unsigned long long best = mine;
#pragma unroll
        for (int mm = 1; mm < 16; mm <<= 1) {
            unsigned long long o = __shfl_xor(best, mm, 16);
            if (o < best) best = o;
        }
        if (best == mine) {
#pragma unroll
            for (int j = 0; j < 9; ++j) keys[j] = keys[j+1];
            keys[9] = ~0ULL;
            int col = (int)(best & 0xFFFFFFFFu);
            idxo[gr * KNB + it] = col;
            atomicAdd(&cnt[bm * NNODE + col], 1);
        }
    }
}

// ---------------------------------------------------------------------------
// CSR build (unchanged)
// ---------------------------------------------------------------------------
__global__ __launch_bounds__(256) void k_scan(const int* __restrict__ cnt,
                                              int* __restrict__ offs) {
    __shared__ int part[256];
    int bm = blockIdx.x, t = threadIdx.x;
    int base = bm * 1024 + t * 4;
    int c0 = cnt[base], c1 = cnt[base+1], c2 = cnt[base+2], c3 = cnt[base+3];
    int ps = c0 + c1 + c2 + c3;
    part[t] = ps;
    __syncthreads();
    for (int off = 1; off < 256; off <<= 1) {
        int add = (t >= off) ? part[t - off] : 0;
        __syncthreads();
        part[t] += add;
        __syncthreads();
    }
    int e0 = part[t] - ps;
    int gb = bm * (NNODE * KNB);
    offs[base]   = gb + e0;
    offs[base+1] = gb + e0 + c0;
    offs[base+2] = gb + e0 + c0 + c1;
    offs[base+3] = gb + e0 + c0 + c1 + c2;
}

__global__ __launch_bounds__(256) void k_fill(const int* __restrict__ idxb,
                                              const int* __restrict__ offs,
                                              int* __restrict__ fill,
                                              int* __restrict__ adj) {
    int i = blockIdx.x * 256 + threadIdx.x;
    int g = i / 10;
    int bm = g >> 10;
    int e  = idxb[i];
    int eg = (bm << 10) + e;
    int pos = atomicAdd(&fill[eg], 1);
    adj[offs[eg] + pos] = g;
}

// ---------------------------------------------------------------------------
// kNN edge gather v2: 32 threads/edge (float4/lane), 8 edges/block,
// 2-way unrolled member loop for MLP.  Ek[e] = (1/De) * sum Xt[members]
// ---------------------------------------------------------------------------
__global__ __launch_bounds__(256) void k_edge(const float* __restrict__ Xt,
                                              const int* __restrict__ offs,
                                              const int* __restrict__ cnt,
                                              const int* __restrict__ adj,
                                              unsigned short* __restrict__ Ek) {
    int tid = threadIdx.x;
    int e = blockIdx.x * 8 + (tid >> 5);
    int l = tid & 31;
    int start = offs[e];
    int num = cnt[e];
    float4 acc = {0.f, 0.f, 0.f, 0.f};
    int i = 0;
    for (; i + 1 < num; i += 2) {
        int g0 = adj[start + i];
        int g1 = adj[start + i + 1];
        float4 a = *(const float4*)(Xt + (size_t)g0 * 128 + l * 4);
        float4 b = *(const float4*)(Xt + (size_t)g1 * 128 + l * 4);
        acc.x += a.x + b.x; acc.y += a.y + b.y;
        acc.z += a.z + b.z; acc.w += a.w + b.w;
    }
    if (i < num) {
        int g0 = adj[start + i];
        float4 a = *(const float4*)(Xt + (size_t)g0 * 128 + l * 4);
        acc.x += a.x; acc.y += a.y; acc.z += a.z; acc.w += a.w;
    }
    float scale = (num > 0) ? 1.0f / (float)num : 0.0f;
    ushort4 o;
    o.x = f2bf(acc.x * scale);
    o.y = f2bf(acc.y * scale);
    o.z = f2bf(acc.z * scale);
    o.w = f2bf(acc.w * scale);
    *(ushort4*)(Ek + (size_t)e * 128 + l * 4) = o;
}

// ---------------------------------------------------------------------------
// Cluster edges (unchanged)
// ---------------------------------------------------------------------------
__global__ __launch_bounds__(256) void k_clus(const float* __restrict__ Xt,
                                              const float* __restrict__ Hc,
                                              float* __restrict__ Ec,
                                              float* __restrict__ Dcv) {
    int tid = threadIdx.x;
    int bm = blockIdx.x >> 3;
    int ch = blockIdx.x & 7;
    int f = tid & 127;
    int h = tid >> 7;
    int c0 = h * 5;
    float acc[5]  = {0.f,0.f,0.f,0.f,0.f};
    float dacc[5] = {0.f,0.f,0.f,0.f,0.f};
    int n0 = ch * 128;
    for (int n = n0; n < n0 + 128; ++n) {
        size_t g = (size_t)bm * NNODE + n;
        float xv = Xt[g * 128 + f];
#pragma unroll
        for (int j = 0; j < 5; ++j) {
            float hv = Hc[g * 10 + c0 + j];
            acc[j]  += hv * xv;
            dacc[j] += hv;
        }
    }
#pragma unroll
    for (int j = 0; j < 5; ++j)
        atomicAdd(&Ec[((size_t)bm * 10 + c0 + j) * 128 + f], acc[j]);
    if (f == 0) {
#pragma unroll
        for (int j = 0; j < 5; ++j) atomicAdd(&Dcv[bm * 10 + c0 + j], dacc[j]);
    }
}

__global__ __launch_bounds__(256) void k_escale(float* __restrict__ Ec,
                                                const float* __restrict__ Dcv) {
    int i = blockIdx.x * 256 + threadIdx.x;
    float d = Dcv[i >> 7];
    Ec[i] = (d > 0.f) ? Ec[i] / d : 0.f;
}

// ---------------------------------------------------------------------------
// Final v2: 32 threads/node (float4/lane), 8 nodes/block.
// out = ELU( (sum_k Ek[idx_k] + sum_c Hc[c]*Ec[c]) / 11 ), transposed layout.
// ---------------------------------------------------------------------------
__global__ __launch_bounds__(256) void k_final(const unsigned short* __restrict__ Ek,
                                               const float* __restrict__ Ec,
                                               const float* __restrict__ Hc,
                                               const int* __restrict__ idxb,
                                               float* __restrict__ out) {
    int tid = threadIdx.x;
    int g = blockIdx.x * 8 + (tid >> 5);
    int l = tid & 31;
    int bm = g >> 10, n = g & 1023;
    const int* ip = idxb + (size_t)g * 10;
    const unsigned short* ekb = Ek + ((size_t)bm << 10) * 128 + l * 4;

    float4 acc = {0.f, 0.f, 0.f, 0.f};
    // kNN part: 10 independent 8B bf16x4 loads (indices broadcast via L1)
#pragma unroll
    for (int k = 0; k < 10; k += 2) {
        int e0 = ip[k], e1 = ip[k + 1];
        ushort4 u0 = *(const ushort4*)(ekb + (size_t)e0 * 128);
        ushort4 u1 = *(const ushort4*)(ekb + (size_t)e1 * 128);
        acc.x += bfu(u0.x) + bfu(u1.x);
        acc.y += bfu(u0.y) + bfu(u1.y);
        acc.z += bfu(u0.z) + bfu(u1.z);
        acc.w += bfu(u0.w) + bfu(u1.w);
    }
    // cluster part
    const float* hp  = Hc + (size_t)g * 10;
    const float* ecp = Ec + (size_t)bm * 10 * 128 + l * 4;
#pragma unroll
    for (int c = 0; c < 10; ++c) {
        float hv = hp[c];
        float4 ec = *(const float4*)(ecp + c * 128);
        acc.x += hv * ec.x; acc.y += hv * ec.y;
        acc.z += hv * ec.z; acc.w += hv * ec.w;
    }
    float4 r;
    r.x = acc.x * (1.0f / 11.0f);
    r.y = acc.y * (1.0f / 11.0f);
    r.z = acc.z * (1.0f / 11.0f);
    r.w = acc.w * (1.0f / 11.0f);
    r.x = (r.x > 0.f) ? r.x : expm1f(r.x);
    r.y = (r.y > 0.f) ? r.y : expm1f(r.y);
    r.z = (r.z > 0.f) ? r.z : expm1f(r.z);
    r.w = (r.w > 0.f) ? r.w : expm1f(r.w);
    int b = bm >> 3, m = bm & 7;
    *(float4*)(out + (((size_t)b * NNODE + n) * 8 + m) * 128 + l * 4) = r;
}

// ---------------------------------------------------------------------------
extern "C" void kernel_launch(void* const* d_in, const int* in_sizes, int n_in,
                              void* d_out, int out_size, void* d_ws, size_t ws_size,
                              hipStream_t stream) {
    const void* x   = d_in[0];
    const void* Wp  = d_in[1];
    const void* Wpb = d_in[2];
    const void* Cm  = d_in[3];
    const void* Th  = d_in[4];
    const void* Thb = d_in[5];
    float* ws = (float*)d_ws;

    if (ws_size < OFF_END * sizeof(float)) return;

    _Float16* Zh = (_Float16*)(ws + OFF_Z);
    _Float16* Zl = (_Float16*)(ws + OFF_Z + 1048576);
    float* sqv  = ws + OFF_SQ;
    float* Hc   = ws + OFF_HC;
    int*   idxb = (int*)(ws + OFF_IDX);
    int*   cnt  = (int*)(ws + OFF_CNT);
    int*   fill = (int*)(ws + OFF_FILL);
    float* Ec   = ws + OFF_EC;
    float* Dcv  = ws + OFF_DCV;
    int*   offs = (int*)(ws + OFF_OFFS);
    int*   adj  = (int*)(ws + OFF_ADJ);
    int*   flag = (int*)(ws + OFF_FLAG);
    unsigned short* Ek = (unsigned short*)(ws + OFF_Z);  // overlays dead Zh/Zl
    float* Xt  = (float*)d_out;
    float* out = (float*)d_out;

    k_probe <<<1, 256, 0, stream>>>((const unsigned int*)x, flag);
    k_zero  <<<(int)((ZERO_N + 255) / 256), 256, 0, stream>>>(ws + OFF_CNT, (int)ZERO_N);
    k_proj  <<<1024, 256, 0, stream>>>(x, Wp, Wpb, Cm, flag, Zh, Zl, sqv, Hc);
    k_topk  <<<2048, 256, 0, stream>>>(Zh, Zl, sqv, idxb, cnt);
    k_scan  <<<32,   256, 0, stream>>>(cnt, offs);
    k_fill  <<<1280, 256, 0, stream>>>(idxb, offs, fill, adj);
    k_theta <<<1024, 256, 0, stream>>>(x, Th, Thb, flag, Xt);
    k_edge  <<<4096, 256, 0, stream>>>(Xt, offs, cnt, adj, Ek);
    k_clus  <<<256,  256, 0, stream>>>(Xt, Hc, Ec, Dcv);
    k_escale<<<160,  256, 0, stream>>>(Ec, Dcv);
    k_final <<<4096, 256, 0, stream>>>(Ek, Ec, Hc, idxb, out);
}